// Round 8
// baseline (131.616 us; speedup 1.0000x reference)
//
#include <hip/hip_runtime.h>
#include <hip/hip_bf16.h>
#include <stdint.h>

typedef __attribute__((ext_vector_type(8))) __bf16 bf16x8;
typedef __attribute__((ext_vector_type(8))) short  short8;
typedef __attribute__((ext_vector_type(4))) float  f32x4;

#define MFMA16(a, b, c) __builtin_amdgcn_mfma_f32_16x16x32_bf16((a), (b), (c), 0, 0, 0)

__device__ __forceinline__ unsigned short f32_bf16(float f) {
  union { float f; unsigned u; } v; v.f = f;
  unsigned r = v.u + 0x7FFFu + ((v.u >> 16) & 1u);
  return (unsigned short)(r >> 16);
}

// async global->LDS, 16B per lane; LDS dest is wave-uniform base (+lane*16 by HW)
__device__ __forceinline__ void gload16(const unsigned short* g, unsigned short* l) {
  __builtin_amdgcn_global_load_lds(
      (const __attribute__((address_space(1))) unsigned int*)(g),
      (__attribute__((address_space(3))) unsigned int*)(l), 16, 0, 0);
}

// ---------------- fp32 -> bf16 convert (all 3 inputs, one launch) ----------------
__global__ void cvt3_kernel(const float* __restrict__ a, int na4,
                            const float* __restrict__ b, int nb4,
                            const float* __restrict__ c, int nc4,
                            unsigned short* __restrict__ oa,
                            unsigned short* __restrict__ ob,
                            unsigned short* __restrict__ oc) {
  int total = na4 + nb4 + nc4;
  for (int i = blockIdx.x * blockDim.x + threadIdx.x; i < total; i += gridDim.x * blockDim.x) {
    const float* src; unsigned short* dst; int j = i;
    if (j < na4) { src = a; dst = oa; }
    else if (j - na4 < nb4) { j -= na4; src = b; dst = ob; }
    else { j -= na4 + nb4; src = c; dst = oc; }
    float4 v = reinterpret_cast<const float4*>(src)[j];
    ushort4 o4;
    o4.x = f32_bf16(v.x); o4.y = f32_bf16(v.y);
    o4.z = f32_bf16(v.z); o4.w = f32_bf16(v.w);
    reinterpret_cast<ushort4*>(dst)[j] = o4;
  }
}

// ---------------- QKV GEMM: 256x256 8-phase (T3+T4+T5), BK=64 ----------------
__global__ __launch_bounds__(512, 2) void gemm_qkv_8ph(const unsigned short* __restrict__ A,
                                                       const unsigned short* __restrict__ Bm,
                                                       unsigned short* __restrict__ qkv) {
  extern __shared__ unsigned short SM[];  // 65536 elems = 131072 B
  const int tid  = threadIdx.x;
  const int lane = tid & 63;
  const int w    = tid >> 6;          // 0..7
  const int wr   = w >> 2, wc = w & 3;
  const int l16  = lane & 15, lh = lane >> 4;
  const int sw   = l16 & 7;
  const int m0   = blockIdx.y * 256;
  const int n0   = blockIdx.x * 256;

  f32x4 acc[8][4];
#pragma unroll
  for (int mi = 0; mi < 8; ++mi)
#pragma unroll
    for (int ni = 0; ni < 4; ++ni) acc[mi][ni] = 0.f;

  const int r0 = tid >> 3,         h0 = (tid & 7) ^ (r0 & 7);
  const int r1 = (tid + 512) >> 3, h1 = (tid & 7) ^ (r1 & 7);
  const unsigned short* Asrc[2][2];
  const unsigned short* Bsrc[2][2];
  Asrc[0][0] = A + (size_t)(m0 + r0) * 1024 + h0 * 8;
  Asrc[0][1] = A + (size_t)(m0 + r1) * 1024 + h1 * 8;
  Asrc[1][0] = A + (size_t)(m0 + 128 + r0) * 1024 + h0 * 8;
  Asrc[1][1] = A + (size_t)(m0 + 128 + r1) * 1024 + h1 * 8;
  Bsrc[0][0] = Bm + (size_t)(n0 + r0) * 1024 + h0 * 8;
  Bsrc[0][1] = Bm + (size_t)(n0 + r1) * 1024 + h1 * 8;
  Bsrc[1][0] = Bm + (size_t)(n0 + 128 + r0) * 1024 + h0 * 8;
  Bsrc[1][1] = Bm + (size_t)(n0 + 128 + r1) * 1024 + h1 * 8;
  const int ld0 = (w * 64) * 8;
  const int ld1 = (512 + w * 64) * 8;

#define STAGE_A(buf, h, U) do { \
    gload16(Asrc[h][0] + (U) * 64, SM + (buf) * 32768 + (h) * 8192 + ld0); \
    gload16(Asrc[h][1] + (U) * 64, SM + (buf) * 32768 + (h) * 8192 + ld1); } while (0)
#define STAGE_B(buf, h, U) do { \
    gload16(Bsrc[h][0] + (U) * 64, SM + (buf) * 32768 + 16384 + (h) * 8192 + ld0); \
    gload16(Bsrc[h][1] + (U) * 64, SM + (buf) * 32768 + 16384 + (h) * 8192 + ld1); } while (0)

  STAGE_A(0, 0, 0); STAGE_A(0, 1, 0);
  STAGE_B(0, 0, 0); STAGE_B(0, 1, 0);
  STAGE_B(1, 0, 1); STAGE_B(1, 1, 1);
  asm volatile("s_waitcnt vmcnt(4)" ::: "memory");
  __builtin_amdgcn_s_barrier();

  const int NT = 16;  // K/64
#pragma unroll 2
  for (int U = 0; U < NT; ++U) {
    const int b = U & 1;
    const unsigned short* Ab = SM + b * 32768 + wr * 8192;
    const unsigned short* Bb = SM + b * 32768 + 16384 + (wc >> 1) * 8192;
    const int rB = (wc & 1) * 64;
    bf16x8 bfr[4][2], af[2][2];

#define LDA(i, j) (*(const bf16x8*)(Ab + (((i) * 16 + l16) * 8 + (((j) * 4 + lh) ^ sw)) * 8))
#define LDB(n, j) (*(const bf16x8*)(Bb + (((rB + (n) * 16 + l16)) * 8 + (((j) * 4 + lh) ^ sw)) * 8))
#define PHASE_MFMA(p) \
    __builtin_amdgcn_s_setprio(1); \
    _Pragma("unroll") \
    for (int n = 0; n < 4; ++n) { \
      acc[2*(p)][n]   = MFMA16(af[0][0], bfr[n][0], acc[2*(p)][n]); \
      acc[2*(p)][n]   = MFMA16(af[0][1], bfr[n][1], acc[2*(p)][n]); \
      acc[2*(p)+1][n] = MFMA16(af[1][0], bfr[n][0], acc[2*(p)+1][n]); \
      acc[2*(p)+1][n] = MFMA16(af[1][1], bfr[n][1], acc[2*(p)+1][n]); \
    } \
    __builtin_amdgcn_s_setprio(0);

    af[0][0] = LDA(0, 0); af[0][1] = LDA(0, 1);
    af[1][0] = LDA(1, 0); af[1][1] = LDA(1, 1);
#pragma unroll
    for (int n = 0; n < 4; ++n) { bfr[n][0] = LDB(n, 0); bfr[n][1] = LDB(n, 1); }
    if (U + 1 < NT) STAGE_A(b ^ 1, 0, U + 1);
    __builtin_amdgcn_s_barrier();
    PHASE_MFMA(0)
    __builtin_amdgcn_s_barrier();
    af[0][0] = LDA(2, 0); af[0][1] = LDA(2, 1);
    af[1][0] = LDA(3, 0); af[1][1] = LDA(3, 1);
    if (U + 1 < NT) STAGE_A(b ^ 1, 1, U + 1);
    __builtin_amdgcn_s_barrier();
    PHASE_MFMA(1)
    __builtin_amdgcn_s_barrier();
    af[0][0] = LDA(4, 0); af[0][1] = LDA(4, 1);
    af[1][0] = LDA(5, 0); af[1][1] = LDA(5, 1);
    if (U + 2 < NT) STAGE_B(b, 0, U + 2);
    __builtin_amdgcn_s_barrier();
    PHASE_MFMA(2)
    __builtin_amdgcn_s_barrier();
    af[0][0] = LDA(6, 0); af[0][1] = LDA(6, 1);
    af[1][0] = LDA(7, 0); af[1][1] = LDA(7, 1);
    if (U + 2 < NT) STAGE_B(b, 1, U + 2);
    __builtin_amdgcn_s_barrier();
    PHASE_MFMA(3)
    asm volatile("s_waitcnt vmcnt(4)" ::: "memory");
    __builtin_amdgcn_s_barrier();
#undef LDA
#undef LDB
#undef PHASE_MFMA
  }

  __syncthreads();
  unsigned short* Ep = SM + w * 8192;
  const int gn0 = n0 + wc * 64;
  const int cc  = gn0 >> 10;
  const int hh2 = (gn0 & 1023) >> 6;
  const int gm0 = m0 + wr * 128;
  const int bb2 = gm0 >> 11;
  const int ss0 = gm0 & 2047;
  const int bh2 = bb2 * 16 + hh2;

  if (cc < 2) {
    const float qsc = (cc == 0) ? 0.18033688f : 1.0f;  // 1/sqrt(64)*log2(e)
#pragma unroll
    for (int mi = 0; mi < 8; ++mi)
#pragma unroll
      for (int ni = 0; ni < 4; ++ni)
#pragma unroll
        for (int r = 0; r < 4; ++r) {
          int row = mi * 16 + lh * 4 + r;
          int col = (ni * 16 + l16) ^ (lh << 3);
          Ep[row * 64 + col] = f32_bf16(acc[mi][ni][r] * qsc);
        }
    unsigned short* qk = qkv + (((size_t)cc * 32 + bh2) * 2048 + ss0) * 64;
#pragma unroll
    for (int it = 0; it < 16; ++it) {
      int ci = it * 64 + lane;
      int row = ci >> 3, c = ci & 7;
      short8 vv = *(const short8*)(Ep + row * 64 + ((c ^ ((row >> 2) & 3)) * 8));
      *(short8*)(qk + (size_t)row * 64 + c * 8) = vv;
    }
  } else {
#pragma unroll
    for (int mi = 0; mi < 8; ++mi)
#pragma unroll
      for (int ni = 0; ni < 4; ++ni) {
        int dk = ni * 16 + l16;
        int ssl = mi * 16 + lh * 4;
        unsigned lo, hi;
        asm("v_cvt_pk_bf16_f32 %0, %1, %2" : "=v"(lo) : "v"(acc[mi][ni][0]), "v"(acc[mi][ni][1]));
        asm("v_cvt_pk_bf16_f32 %0, %1, %2" : "=v"(hi) : "v"(acc[mi][ni][2]), "v"(acc[mi][ni][3]));
        int off = dk * 128 + (ssl ^ ((dk & 7) << 3));
        *(uint2*)(Ep + off) = make_uint2(lo, hi);
      }
    unsigned short* vt = qkv + (size_t)8388608 + (size_t)bh2 * 64 * 2048 + ss0;
#pragma unroll
    for (int it = 0; it < 16; ++it) {
      int ci = it * 64 + lane;
      int dk = ci >> 4, c = ci & 15;
      short8 vv = *(const short8*)(Ep + dk * 128 + ((c ^ (dk & 7)) * 8));
      *(short8*)(vt + (size_t)dk * 2048 + c * 8) = vv;
    }
  }
#undef STAGE_A
#undef STAGE_B
}

// ---------------- out-proj GEMM, C = A * B^T (m97 128^2 structure) ----------------
__global__ __launch_bounds__(256) void gemm_out(const unsigned short* __restrict__ A,
                                                const unsigned short* __restrict__ Bm,
                                                float* __restrict__ C,
                                                int M, int N, int K) {
  extern __shared__ unsigned short SM[];  // 32768 bytes
  unsigned short* As = SM;
  unsigned short* Bs = SM + 4096;
  const int tid  = threadIdx.x;
  const int lane = tid & 63;
  const int wid  = tid >> 6;
  const int wr   = wid >> 1, wc = wid & 1;
  const int l16  = lane & 15, lh = lane >> 4;
  const int m0   = blockIdx.y * 128;
  const int n0   = blockIdx.x * 128;

  f32x4 acc[4][4];
#pragma unroll
  for (int mi = 0; mi < 4; ++mi)
#pragma unroll
    for (int ni = 0; ni < 4; ++ni) acc[mi][ni] = 0.f;

  const int c0 = tid, c1 = 256 + tid;
  const unsigned short* a0 = A + (size_t)(m0 + (c0 >> 2)) * K + (c0 & 3) * 8;
  const unsigned short* a1 = A + (size_t)(m0 + (c1 >> 2)) * K + (c1 & 3) * 8;
  const unsigned short* b0 = Bm + (size_t)(n0 + (c0 >> 2)) * K + (c0 & 3) * 8;
  const unsigned short* b1 = Bm + (size_t)(n0 + (c1 >> 2)) * K + (c1 & 3) * 8;
  const int d0 = wid * 64 * 8;
  const int d1 = (256 + wid * 64) * 8;

  for (int k0 = 0; k0 < K; k0 += 32) {
    __syncthreads();
    gload16(a0 + k0, As + d0);
    gload16(a1 + k0, As + d1);
    gload16(b0 + k0, Bs + d0);
    gload16(b1 + k0, Bs + d1);
    __syncthreads();
    bf16x8 af[4], bfr[4];
#pragma unroll
    for (int i = 0; i < 4; ++i) {
      af[i]  = *(const bf16x8*)(As + (wr * 64 + i * 16 + l16) * 32 + lh * 8);
      bfr[i] = *(const bf16x8*)(Bs + (wc * 64 + i * 16 + l16) * 32 + lh * 8);
    }
#pragma unroll
    for (int mi = 0; mi < 4; ++mi)
#pragma unroll
      for (int ni = 0; ni < 4; ++ni)
        acc[mi][ni] = MFMA16(af[mi], bfr[ni], acc[mi][ni]);
  }

  __syncthreads();
  float* Ef = (float*)(SM + wid * 4096);
  const int gm0 = m0 + wr * 64;
  const int gn0 = n0 + wc * 64;
#pragma unroll
  for (int p = 0; p < 2; ++p) {
#pragma unroll
    for (int mi = 0; mi < 4; ++mi)
#pragma unroll
      for (int q = 0; q < 2; ++q) {
        int ni = 2 * p + q;
#pragma unroll
        for (int r = 0; r < 4; ++r) {
          int row = mi * 16 + lh * 4 + r;
          int col = (q * 16 + l16) ^ ((row & 7) << 2);
          Ef[row * 32 + col] = acc[mi][ni][r];
        }
      }
#pragma unroll
    for (int it = 0; it < 8; ++it) {
      int ci = it * 64 + lane;
      int row = ci >> 3, c4 = ci & 7;
      float4 vv = *(const float4*)(Ef + row * 32 + ((c4 * 4) ^ ((row & 7) << 2)));
      *(float4*)(&C[(size_t)(gm0 + row) * N + gn0 + p * 32 + c4 * 4]) = vv;
    }
  }
}

// ---------------- causal flash attention (swapped-QK^T, QBLK=32, KVBLK=32) ------
// Q: [bh][2048][64] (prescaled log2e/8), K: [bh][2048][64], Vt: [bh][64][2048].
// 2 waves x 16 q-rows = 32 q/block, 2048 blocks, LDS 18KB -> 8 blocks/CU (16 waves
// resident). Ring map: each CU's 8 resident blocks sum to 260 half-tiles, mixed
// long/short. Swapped QK^T; single-fragment P; defer-max; exp2.
__global__ __launch_bounds__(128) void attn_kernel(const unsigned short* __restrict__ Qg,
                                                   const unsigned short* __restrict__ Kg,
                                                   const unsigned short* __restrict__ Vtg,
                                                   unsigned short* __restrict__ Og) {
  __shared__ unsigned short Ks[2][32 * 64];
  __shared__ unsigned short Vs[2][64 * 32];
  __shared__ unsigned short Pl[2][16 * 32];

  const int tid  = threadIdx.x;       // 0..127
  const int lane = tid & 63;
  const int w    = tid >> 6;          // 0..1
  const int l16  = lane & 15, lh = lane >> 4;
  // balanced per-CU ring map over j = bid>>5 (0..63): k2 fixed per CU, ring 0..7
  const int j    = blockIdx.x >> 5;
  const int k2   = j & 7, ring = j >> 3;
  const int base = (ring >> 1) * 8 + k2;
  const int qt   = (ring & 1) ? (63 - base) : base;   // 32-row q-tile index 0..63
  const int bh   = blockIdx.x & 31;
  const int bb   = bh >> 4, hh = bh & 15;
  const int qb   = qt * 32;
  const int wqb  = qb + w * 16;

  const unsigned short* Qh = Qg + (size_t)bh * (2048 * 64);
  const unsigned short* Kh = Kg + (size_t)bh * (2048 * 64);
  const unsigned short* Vh = Vtg + (size_t)bh * (64 * 2048);

  bf16x8 qf[2];
#pragma unroll
  for (int h2 = 0; h2 < 2; ++h2)
    qf[h2] = *(const bf16x8*)(Qh + (size_t)(wqb + l16) * 64 + h2 * 32 + lh * 8);

  float mreg = 0.f;   // defer-max baseline; slow path handles growth
  float ll   = 0.f;
  f32x4 o[4];
#pragma unroll
  for (int f = 0; f < 4; ++f) o[f] = 0.f;

  const int sw = l16 & 7;

  // K staging: 256 chunks (r=kv 0..31, 8 chunks/row), slots tid, tid+128
  // slot s: r=s>>3, hc=(s&7)^(r&7)  (involutive)
  const int sk0 = tid, sk1 = tid + 128;
  const int rk0 = sk0 >> 3, hk0 = (sk0 & 7) ^ (rk0 & 7);
  const int rk1 = sk1 >> 3, hk1 = (sk1 & 7) ^ (rk1 & 7);
  const unsigned short* kSrc0 = Kh + rk0 * 64 + hk0 * 8;
  const unsigned short* kSrc1 = Kh + rk1 * 64 + hk1 * 8;
  // V staging: 256 chunks (r=dk 0..63, 4 chunks/row), xv(r)=(r+(r>>2))&3
  const int rv0 = sk0 >> 2, hv0 = (sk0 & 3) ^ ((rv0 + (rv0 >> 2)) & 3);
  const int rv1 = sk1 >> 2, hv1 = (sk1 & 3) ^ ((rv1 + (rv1 >> 2)) & 3);
  const unsigned short* vSrc0 = Vh + (size_t)rv0 * 2048 + hv0 * 8;
  const unsigned short* vSrc1 = Vh + (size_t)rv1 * 2048 + hv1 * 8;
  const int lds0 = (w * 64) * 8;           // wave-uniform LDS elem offsets
  const int lds1 = (w * 64 + 128) * 8;

  // precomputed read offsets
  int koff[2][2], voff[4];
#pragma unroll
  for (int tt = 0; tt < 2; ++tt) {
    int krow = tt * 16 + l16;
    koff[tt][0] = krow * 64 + ((lh ^ sw) << 3);
    koff[tt][1] = krow * 64 + (((lh + 4) ^ sw) << 3);
  }
#pragma unroll
  for (int f = 0; f < 4; ++f) {
    int vrow = f * 16 + l16;
    voff[f] = vrow * 32 + ((lh ^ ((vrow + (vrow >> 2)) & 3)) << 3);
  }
  const int pwoff0 = l16 * 32 + (((0 * 4 + lh) ^ (l16 & 6)) << 2);  // tt=0 uint2 slot
  const int pwoff1 = l16 * 32 + (((1 * 4 + lh) ^ (l16 & 6)) << 2);  // tt=1
  const int proff  = l16 * 32 + (((2 * lh) ^ (l16 & 6)) << 2);      // b128 read

  const int ntiles = qt + 1;

  gload16(kSrc0, &Ks[0][lds0]);
  gload16(kSrc1, &Ks[0][lds1]);
  gload16(vSrc0, &Vs[0][lds0]);
  gload16(vSrc1, &Vs[0][lds1]);
  __syncthreads();

  for (int t = 0; t < ntiles; ++t) {
    const int kv0 = t * 32;
    const int cur = t & 1;
    if (t + 1 < ntiles) {
      const int nk = kv0 + 32;
      gload16(kSrc0 + (size_t)nk * 64, &Ks[cur ^ 1][lds0]);
      gload16(kSrc1 + (size_t)nk * 64, &Ks[cur ^ 1][lds1]);
      gload16(vSrc0 + nk, &Vs[cur ^ 1][lds0]);
      gload16(vSrc1 + nk, &Vs[cur ^ 1][lds1]);
    }

    if (kv0 <= wqb + 15) {  // wave-uniform skip of fully-masked tiles
      const unsigned short* Kb = Ks[cur];
      const unsigned short* Vb = Vs[cur];

      // S^T[tt]: kv = kv0 + tt*16 + lh*4 + r, q = l16
      f32x4 st[2];
#pragma unroll
      for (int tt = 0; tt < 2; ++tt) {
        bf16x8 kf0 = *(const bf16x8*)(Kb + koff[tt][0]);
        bf16x8 kf1 = *(const bf16x8*)(Kb + koff[tt][1]);
        f32x4 a = {0.f, 0.f, 0.f, 0.f};
        a = MFMA16(kf0, qf[0], a);
        a = MFMA16(kf1, qf[1], a);
        st[tt] = a;
      }

      if (kv0 + 31 > wqb) {  // causal mask (diag tiles only)
        int qrow = wqb + l16;
#pragma unroll
        for (int tt = 0; tt < 2; ++tt) {
          int kvb = kv0 + tt * 16 + lh * 4;
#pragma unroll
          for (int r = 0; r < 4; ++r)
            if (kvb + r > qrow) st[tt][r] = -__builtin_inff();
        }
      }

      // defer-max: fast path has no shuffles, no rescale
      float pm = fmaxf(fmaxf(st[0][0], st[0][1]), fmaxf(st[0][2], st[0][3]));
      pm = fmaxf(pm, fmaxf(fmaxf(st[1][0], st[1][1]), fmaxf(st[1][2], st[1][3])));
      if (!__all(pm <= mreg + 8.f)) {
        float t0 = pm;
        t0 = fmaxf(t0, __shfl_xor(t0, 16));
        t0 = fmaxf(t0, __shfl_xor(t0, 32));
        float mn = fmaxf(mreg, t0);
        float er = exp2f(mreg - mn);
        mreg = mn;
        ll *= er;
#pragma unroll
        for (int r = 0; r < 4; ++r) {
          float e = __shfl(er, lh * 4 + r);
#pragma unroll
          for (int f = 0; f < 4; ++f) o[f][r] *= e;
        }
      }

      // P = exp2(st - m): 2 packed uint2 LDS writes; row-sum via 2 shuffles
      unsigned short* Pw = Pl[w];
      float ps;
      {
        float p0 = exp2f(st[0][0] - mreg), p1 = exp2f(st[0][1] - mreg);
        float p2 = exp2f(st[0][2] - mreg), p3 = exp2f(st[0][3] - mreg);
        float q0 = exp2f(st[1][0] - mreg), q1 = exp2f(st[1][1] - mreg);
        float q2 = exp2f(st[1][2] - mreg), q3 = exp2f(st[1][3] - mreg);
        ps = ((p0 + p1) + (p2 + p3)) + ((q0 + q1) + (q2 + q3));
        unsigned w0, w1, w2, w3;
        asm("v_cvt_pk_bf16_f32 %0, %1, %2" : "=v"(w0) : "v"(p0), "v"(p1));
        asm("v_cvt_pk_bf16_f32 %0, %1, %2" : "=v"(w1) : "v"(p2), "v"(p3));
        asm("v_cvt_pk_bf16_f32 %0, %1, %2" : "=v"(w2) : "v"(q0), "v"(q1));
        asm("v_cvt_pk_bf16_f32 %0, %1, %2" : "=v"(w3) : "v"(q2), "v"(q3));
        *(uint2*)(Pw + pwoff0) = make_uint2(w0, w1);
        *(uint2*)(Pw + pwoff1) = make_uint2(w2, w3);
      }
      ps += __shfl_xor(ps, 16);
      ps += __shfl_xor(ps, 32);
      ll += ps;

      // PV: single P fragment (kv 0..31), 4 V frags
      bf16x8 pf = *(const bf16x8*)(Pw + proff);
#pragma unroll
      for (int f = 0; f < 4; ++f) {
        bf16x8 vf = *(const bf16x8*)(Vb + voff[f]);
        o[f] = MFMA16(pf, vf, o[f]);
      }
    }
    __syncthreads();
  }

  unsigned short* op = Og + (size_t)bb * 2048 * 1024 + (size_t)hh * 64;
#pragma unroll
  for (int r = 0; r < 4; ++r) {
    float linv = 1.f / __shfl(ll, lh * 4 + r);
    int row = wqb + lh * 4 + r;
#pragma unroll
    for (int f = 0; f < 4; ++f)
      op[(size_t)row * 1024 + f * 16 + l16] = f32_bf16(o[f][r] * linv);
  }
}

extern "C" void kernel_launch(void* const* d_in, const int* in_sizes, int n_in,
                              void* d_out, int out_size, void* d_ws, size_t ws_size,
                              hipStream_t stream) {
  const float* x    = (const float*)d_in[0];
  const float* Wqkv = (const float*)d_in[1];
  const float* Wout = (const float*)d_in[2];
  float* out = (float*)d_out;

  char* ws = (char*)d_ws;
  unsigned short* xb  = (unsigned short*)(ws);                              // 8 MB
  unsigned short* wqb = (unsigned short*)(ws + (size_t)8 * 1024 * 1024);    // 6 MB
  unsigned short* wob = (unsigned short*)(ws + (size_t)14 * 1024 * 1024);   // 2 MB
  unsigned short* qkv = (unsigned short*)(ws + (size_t)16 * 1024 * 1024);   // 24 MB
  unsigned short* att = (unsigned short*)(ws + (size_t)40 * 1024 * 1024);   // 8 MB

  static bool attr_set = false;
  if (!attr_set) {
    hipFuncSetAttribute((const void*)gemm_qkv_8ph,
                        hipFuncAttributeMaxDynamicSharedMemorySize, 131072);
    attr_set = true;
  }

  cvt3_kernel<<<2048, 256, 0, stream>>>(x, 4194304 / 4, Wqkv, 3145728 / 4,
                                        Wout, 1048576 / 4, xb, wqb, wob);

  // QKV projection (8-phase 256^2) -> Q,K [bh][s][dk] (Q exp2-scaled); V^T [bh][dk][s]
  gemm_qkv_8ph<<<dim3(12, 16), 512, 131072, stream>>>(xb, wqb, qkv);

  const unsigned short* Qp  = qkv;
  const unsigned short* Kp  = qkv + 4194304;
  const unsigned short* Vtp = qkv + 8388608;
  attn_kernel<<<2048, 128, 0, stream>>>(Qp, Kp, Vtp, att);

  // output projection -> fp32 out
  gemm_out<<<dim3(8, 32), 256, 32768, stream>>>(att, wob, out, 4096, 1024, 1024);
}

// Round 9
// 126.694 us; speedup vs baseline: 1.0388x; 1.0388x over previous
//
#include <hip/hip_runtime.h>
#include <hip/hip_bf16.h>
#include <stdint.h>

typedef __attribute__((ext_vector_type(8)))  __bf16 bf16x8;
typedef __attribute__((ext_vector_type(8)))  short  short8;
typedef __attribute__((ext_vector_type(4)))  float  f32x4;
typedef __attribute__((ext_vector_type(16))) float  f32x16;

#define MFMA16(a, b, c) __builtin_amdgcn_mfma_f32_16x16x32_bf16((a), (b), (c), 0, 0, 0)
#define MFMA32(a, b, c) __builtin_amdgcn_mfma_f32_32x32x16_bf16((a), (b), (c), 0, 0, 0)

__device__ __forceinline__ unsigned short f32_bf16(float f) {
  union { float f; unsigned u; } v; v.f = f;
  unsigned r = v.u + 0x7FFFu + ((v.u >> 16) & 1u);
  return (unsigned short)(r >> 16);
}

// async global->LDS, 16B per lane; LDS dest is wave-uniform base (+lane*16 by HW)
__device__ __forceinline__ void gload16(const unsigned short* g, unsigned short* l) {
  __builtin_amdgcn_global_load_lds(
      (const __attribute__((address_space(1))) unsigned int*)(g),
      (__attribute__((address_space(3))) unsigned int*)(l), 16, 0, 0);
}

// ---------------- fp32 -> bf16 convert (all 3 inputs, one launch) ----------------
__global__ void cvt3_kernel(const float* __restrict__ a, int na4,
                            const float* __restrict__ b, int nb4,
                            const float* __restrict__ c, int nc4,
                            unsigned short* __restrict__ oa,
                            unsigned short* __restrict__ ob,
                            unsigned short* __restrict__ oc) {
  int total = na4 + nb4 + nc4;
  for (int i = blockIdx.x * blockDim.x + threadIdx.x; i < total; i += gridDim.x * blockDim.x) {
    const float* src; unsigned short* dst; int j = i;
    if (j < na4) { src = a; dst = oa; }
    else if (j - na4 < nb4) { j -= na4; src = b; dst = ob; }
    else { j -= na4 + nb4; src = c; dst = oc; }
    float4 v = reinterpret_cast<const float4*>(src)[j];
    ushort4 o4;
    o4.x = f32_bf16(v.x); o4.y = f32_bf16(v.y);
    o4.z = f32_bf16(v.z); o4.w = f32_bf16(v.w);
    reinterpret_cast<ushort4*>(dst)[j] = o4;
  }
}

// ---------------- QKV GEMM: 256x256 8-phase (T3+T4+T5), BK=64 ----------------
__global__ __launch_bounds__(512, 2) void gemm_qkv_8ph(const unsigned short* __restrict__ A,
                                                       const unsigned short* __restrict__ Bm,
                                                       unsigned short* __restrict__ qkv) {
  extern __shared__ unsigned short SM[];  // 65536 elems = 131072 B
  const int tid  = threadIdx.x;
  const int lane = tid & 63;
  const int w    = tid >> 6;          // 0..7
  const int wr   = w >> 2, wc = w & 3;
  const int l16  = lane & 15, lh = lane >> 4;
  const int sw   = l16 & 7;
  const int m0   = blockIdx.y * 256;
  const int n0   = blockIdx.x * 256;

  f32x4 acc[8][4];
#pragma unroll
  for (int mi = 0; mi < 8; ++mi)
#pragma unroll
    for (int ni = 0; ni < 4; ++ni) acc[mi][ni] = 0.f;

  const int r0 = tid >> 3,         h0 = (tid & 7) ^ (r0 & 7);
  const int r1 = (tid + 512) >> 3, h1 = (tid & 7) ^ (r1 & 7);
  const unsigned short* Asrc[2][2];
  const unsigned short* Bsrc[2][2];
  Asrc[0][0] = A + (size_t)(m0 + r0) * 1024 + h0 * 8;
  Asrc[0][1] = A + (size_t)(m0 + r1) * 1024 + h1 * 8;
  Asrc[1][0] = A + (size_t)(m0 + 128 + r0) * 1024 + h0 * 8;
  Asrc[1][1] = A + (size_t)(m0 + 128 + r1) * 1024 + h1 * 8;
  Bsrc[0][0] = Bm + (size_t)(n0 + r0) * 1024 + h0 * 8;
  Bsrc[0][1] = Bm + (size_t)(n0 + r1) * 1024 + h1 * 8;
  Bsrc[1][0] = Bm + (size_t)(n0 + 128 + r0) * 1024 + h0 * 8;
  Bsrc[1][1] = Bm + (size_t)(n0 + 128 + r1) * 1024 + h1 * 8;
  const int ld0 = (w * 64) * 8;
  const int ld1 = (512 + w * 64) * 8;

#define STAGE_A(buf, h, U) do { \
    gload16(Asrc[h][0] + (U) * 64, SM + (buf) * 32768 + (h) * 8192 + ld0); \
    gload16(Asrc[h][1] + (U) * 64, SM + (buf) * 32768 + (h) * 8192 + ld1); } while (0)
#define STAGE_B(buf, h, U) do { \
    gload16(Bsrc[h][0] + (U) * 64, SM + (buf) * 32768 + 16384 + (h) * 8192 + ld0); \
    gload16(Bsrc[h][1] + (U) * 64, SM + (buf) * 32768 + 16384 + (h) * 8192 + ld1); } while (0)

  STAGE_A(0, 0, 0); STAGE_A(0, 1, 0);
  STAGE_B(0, 0, 0); STAGE_B(0, 1, 0);
  STAGE_B(1, 0, 1); STAGE_B(1, 1, 1);
  asm volatile("s_waitcnt vmcnt(4)" ::: "memory");
  __builtin_amdgcn_s_barrier();

  const int NT = 16;  // K/64
#pragma unroll 2
  for (int U = 0; U < NT; ++U) {
    const int b = U & 1;
    const unsigned short* Ab = SM + b * 32768 + wr * 8192;
    const unsigned short* Bb = SM + b * 32768 + 16384 + (wc >> 1) * 8192;
    const int rB = (wc & 1) * 64;
    bf16x8 bfr[4][2], af[2][2];

#define LDA(i, j) (*(const bf16x8*)(Ab + (((i) * 16 + l16) * 8 + (((j) * 4 + lh) ^ sw)) * 8))
#define LDB(n, j) (*(const bf16x8*)(Bb + (((rB + (n) * 16 + l16)) * 8 + (((j) * 4 + lh) ^ sw)) * 8))
#define PHASE_MFMA(p) \
    __builtin_amdgcn_s_setprio(1); \
    _Pragma("unroll") \
    for (int n = 0; n < 4; ++n) { \
      acc[2*(p)][n]   = MFMA16(af[0][0], bfr[n][0], acc[2*(p)][n]); \
      acc[2*(p)][n]   = MFMA16(af[0][1], bfr[n][1], acc[2*(p)][n]); \
      acc[2*(p)+1][n] = MFMA16(af[1][0], bfr[n][0], acc[2*(p)+1][n]); \
      acc[2*(p)+1][n] = MFMA16(af[1][1], bfr[n][1], acc[2*(p)+1][n]); \
    } \
    __builtin_amdgcn_s_setprio(0);

    af[0][0] = LDA(0, 0); af[0][1] = LDA(0, 1);
    af[1][0] = LDA(1, 0); af[1][1] = LDA(1, 1);
#pragma unroll
    for (int n = 0; n < 4; ++n) { bfr[n][0] = LDB(n, 0); bfr[n][1] = LDB(n, 1); }
    if (U + 1 < NT) STAGE_A(b ^ 1, 0, U + 1);
    __builtin_amdgcn_s_barrier();
    PHASE_MFMA(0)
    __builtin_amdgcn_s_barrier();
    af[0][0] = LDA(2, 0); af[0][1] = LDA(2, 1);
    af[1][0] = LDA(3, 0); af[1][1] = LDA(3, 1);
    if (U + 1 < NT) STAGE_A(b ^ 1, 1, U + 1);
    __builtin_amdgcn_s_barrier();
    PHASE_MFMA(1)
    __builtin_amdgcn_s_barrier();
    af[0][0] = LDA(4, 0); af[0][1] = LDA(4, 1);
    af[1][0] = LDA(5, 0); af[1][1] = LDA(5, 1);
    if (U + 2 < NT) STAGE_B(b, 0, U + 2);
    __builtin_amdgcn_s_barrier();
    PHASE_MFMA(2)
    __builtin_amdgcn_s_barrier();
    af[0][0] = LDA(6, 0); af[0][1] = LDA(6, 1);
    af[1][0] = LDA(7, 0); af[1][1] = LDA(7, 1);
    if (U + 2 < NT) STAGE_B(b, 1, U + 2);
    __builtin_amdgcn_s_barrier();
    PHASE_MFMA(3)
    asm volatile("s_waitcnt vmcnt(4)" ::: "memory");
    __builtin_amdgcn_s_barrier();
#undef LDA
#undef LDB
#undef PHASE_MFMA
  }

  __syncthreads();
  unsigned short* Ep = SM + w * 8192;
  const int gn0 = n0 + wc * 64;
  const int cc  = gn0 >> 10;
  const int hh2 = (gn0 & 1023) >> 6;
  const int gm0 = m0 + wr * 128;
  const int bb2 = gm0 >> 11;
  const int ss0 = gm0 & 2047;
  const int bh2 = bb2 * 16 + hh2;

  if (cc < 2) {
    const float qsc = (cc == 0) ? 0.18033688f : 1.0f;  // 1/sqrt(64)*log2(e)
#pragma unroll
    for (int mi = 0; mi < 8; ++mi)
#pragma unroll
      for (int ni = 0; ni < 4; ++ni)
#pragma unroll
        for (int r = 0; r < 4; ++r) {
          int row = mi * 16 + lh * 4 + r;
          int col = (ni * 16 + l16) ^ (lh << 3);
          Ep[row * 64 + col] = f32_bf16(acc[mi][ni][r] * qsc);
        }
    unsigned short* qk = qkv + (((size_t)cc * 32 + bh2) * 2048 + ss0) * 64;
#pragma unroll
    for (int it = 0; it < 16; ++it) {
      int ci = it * 64 + lane;
      int row = ci >> 3, c = ci & 7;
      short8 vv = *(const short8*)(Ep + row * 64 + ((c ^ ((row >> 2) & 3)) * 8));
      *(short8*)(qk + (size_t)row * 64 + c * 8) = vv;
    }
  } else {
#pragma unroll
    for (int mi = 0; mi < 8; ++mi)
#pragma unroll
      for (int ni = 0; ni < 4; ++ni) {
        int dk = ni * 16 + l16;
        int ssl = mi * 16 + lh * 4;
        unsigned lo, hi;
        asm("v_cvt_pk_bf16_f32 %0, %1, %2" : "=v"(lo) : "v"(acc[mi][ni][0]), "v"(acc[mi][ni][1]));
        asm("v_cvt_pk_bf16_f32 %0, %1, %2" : "=v"(hi) : "v"(acc[mi][ni][2]), "v"(acc[mi][ni][3]));
        int off = dk * 128 + (ssl ^ ((dk & 7) << 3));
        *(uint2*)(Ep + off) = make_uint2(lo, hi);
      }
    unsigned short* vt = qkv + (size_t)8388608 + (size_t)bh2 * 64 * 2048 + ss0;
#pragma unroll
    for (int it = 0; it < 16; ++it) {
      int ci = it * 64 + lane;
      int dk = ci >> 4, c = ci & 15;
      short8 vv = *(const short8*)(Ep + dk * 128 + ((c ^ (dk & 7)) * 8));
      *(short8*)(vt + (size_t)dk * 2048 + c * 8) = vv;
    }
  }
#undef STAGE_A
#undef STAGE_B
}

// ---------------- out-proj GEMM, C = A * B^T (m97 128^2 structure) ----------------
__global__ __launch_bounds__(256) void gemm_out(const unsigned short* __restrict__ A,
                                                const unsigned short* __restrict__ Bm,
                                                float* __restrict__ C,
                                                int M, int N, int K) {
  extern __shared__ unsigned short SM[];  // 32768 bytes
  unsigned short* As = SM;
  unsigned short* Bs = SM + 4096;
  const int tid  = threadIdx.x;
  const int lane = tid & 63;
  const int wid  = tid >> 6;
  const int wr   = wid >> 1, wc = wid & 1;
  const int l16  = lane & 15, lh = lane >> 4;
  const int m0   = blockIdx.y * 128;
  const int n0   = blockIdx.x * 128;

  f32x4 acc[4][4];
#pragma unroll
  for (int mi = 0; mi < 4; ++mi)
#pragma unroll
    for (int ni = 0; ni < 4; ++ni) acc[mi][ni] = 0.f;

  const int c0 = tid, c1 = 256 + tid;
  const unsigned short* a0 = A + (size_t)(m0 + (c0 >> 2)) * K + (c0 & 3) * 8;
  const unsigned short* a1 = A + (size_t)(m0 + (c1 >> 2)) * K + (c1 & 3) * 8;
  const unsigned short* b0 = Bm + (size_t)(n0 + (c0 >> 2)) * K + (c0 & 3) * 8;
  const unsigned short* b1 = Bm + (size_t)(n0 + (c1 >> 2)) * K + (c1 & 3) * 8;
  const int d0 = wid * 64 * 8;
  const int d1 = (256 + wid * 64) * 8;

  for (int k0 = 0; k0 < K; k0 += 32) {
    __syncthreads();
    gload16(a0 + k0, As + d0);
    gload16(a1 + k0, As + d1);
    gload16(b0 + k0, Bs + d0);
    gload16(b1 + k0, Bs + d1);
    __syncthreads();
    bf16x8 af[4], bfr[4];
#pragma unroll
    for (int i = 0; i < 4; ++i) {
      af[i]  = *(const bf16x8*)(As + (wr * 64 + i * 16 + l16) * 32 + lh * 8);
      bfr[i] = *(const bf16x8*)(Bs + (wc * 64 + i * 16 + l16) * 32 + lh * 8);
    }
#pragma unroll
    for (int mi = 0; mi < 4; ++mi)
#pragma unroll
      for (int ni = 0; ni < 4; ++ni)
        acc[mi][ni] = MFMA16(af[mi], bfr[ni], acc[mi][ni]);
  }

  __syncthreads();
  float* Ef = (float*)(SM + wid * 4096);
  const int gm0 = m0 + wr * 64;
  const int gn0 = n0 + wc * 64;
#pragma unroll
  for (int p = 0; p < 2; ++p) {
#pragma unroll
    for (int mi = 0; mi < 4; ++mi)
#pragma unroll
      for (int q = 0; q < 2; ++q) {
        int ni = 2 * p + q;
#pragma unroll
        for (int r = 0; r < 4; ++r) {
          int row = mi * 16 + lh * 4 + r;
          int col = (q * 16 + l16) ^ ((row & 7) << 2);
          Ef[row * 32 + col] = acc[mi][ni][r];
        }
      }
#pragma unroll
    for (int it = 0; it < 8; ++it) {
      int ci = it * 64 + lane;
      int row = ci >> 3, c4 = ci & 7;
      float4 vv = *(const float4*)(Ef + row * 32 + ((c4 * 4) ^ ((row & 7) << 2)));
      *(float4*)(&C[(size_t)(gm0 + row) * N + gn0 + p * 32 + c4 * 4]) = vv;
    }
  }
}

// ---------------- causal flash attention: 32x32 MFMA, in-register P (T12) --------
// Q: [bh][2048][64] (prescaled log2e/8), K: [bh][2048][64], Vt: [bh][64][2048].
// 2 waves x 32 q-rows = QBLK 64, KVBLK=64 dbuf, LDS 32KB, grid 1024 (ring map).
// Swapped S^T = mfma(K, Q): lane owns q-col (lane&31). P built in-register via
// v_cvt_pk_bf16_f32 + v_permlane32_swap_b32 -> PV B-operand, zero P LDS traffic.
// O^T accumulated (col=q): rescale is per-lane scalar. Epilogue via LDS bounce.
__global__ __launch_bounds__(128) void attn_kernel(const unsigned short* __restrict__ Qg,
                                                   const unsigned short* __restrict__ Kg,
                                                   const unsigned short* __restrict__ Vtg,
                                                   unsigned short* __restrict__ Og) {
  __shared__ unsigned short Ks[2][64 * 64];
  __shared__ unsigned short Vs[2][64 * 64];

  const int tid  = threadIdx.x;       // 0..127
  const int lane = tid & 63;
  const int w    = tid >> 6;          // 0..1
  const int l31  = lane & 31, hi = lane >> 5;
  // ring map: per-CU block lengths mixed, sums equal (r5-proven)
  const int j    = blockIdx.x >> 5;
  const int ring = j >> 3, k = j & 7;
  const int qt   = (ring == 0) ? 31 - k : (ring == 1) ? k : (ring == 2) ? 23 - k : 8 + k;
  const int bh   = blockIdx.x & 31;
  const int bb   = bh >> 4, hh = bh & 15;
  const int qb   = qt * 64;
  const int wq   = qb + w * 32;
  const int qcol = wq + l31;          // this lane's q-row (column of S^T/O^T)

  const unsigned short* Qh = Qg + (size_t)bh * (2048 * 64);
  const unsigned short* Kh = Kg + (size_t)bh * (2048 * 64);
  const unsigned short* Vh = Vtg + (size_t)bh * (64 * 2048);

  // Q as B-operand: lane holds col q = l31, k-elems dk = ks*16 + hi*8 + j
  bf16x8 qf[4];
#pragma unroll
  for (int ks = 0; ks < 4; ++ks)
    qf[ks] = *(const bf16x8*)(Qh + (size_t)qcol * 64 + ks * 16 + hi * 8);

  f32x16 o0 = 0.f, o1 = 0.f;   // O^T: rows d (dsub 0/1), col q = lane
  float mreg = 0.f, ll = 0.f;  // defer-max baseline 0 (exp2-space)

  // staging: 512 chunk-slots per 8KB tile; thread covers slots i*128+tid, i=0..3
  // slot s holds chunk (r=s>>3, h=(s&7)^(r&7)) - involutive pre-swizzle
  const unsigned short* kSrc[4];
  const unsigned short* vSrc[4];
  int ldso[4];
#pragma unroll
  for (int i = 0; i < 4; ++i) {
    int s = i * 128 + tid;
    int r = s >> 3, h = (s & 7) ^ (r & 7);
    kSrc[i] = Kh + r * 64 + h * 8;
    vSrc[i] = Vh + (size_t)r * 2048 + h * 8;
    ldso[i] = (i * 128 + w * 64) * 8;   // wave-uniform LDS elem offset
  }

  const int swz = l31 & 7;

  // prologue: tile 0 -> buffer 0
#pragma unroll
  for (int i = 0; i < 4; ++i) {
    gload16(kSrc[i], &Ks[0][ldso[i]]);
    gload16(vSrc[i], &Vs[0][ldso[i]]);
  }
  __syncthreads();

  for (int t = 0; t <= qt; ++t) {
    const int kv0 = t * 64;
    const int cur = t & 1;
    if (t < qt) {
#pragma unroll
      for (int i = 0; i < 4; ++i) {
        gload16(kSrc[i] + (size_t)(kv0 + 64) * 64, &Ks[cur ^ 1][ldso[i]]);
        gload16(vSrc[i] + (kv0 + 64), &Vs[cur ^ 1][ldso[i]]);
      }
    }
    const unsigned short* Kb = Ks[cur];
    const unsigned short* Vb = Vs[cur];

    // S^T = K * Q^T: rows kv, cols q. Two 32-kv subtiles; k = dk (4 slices).
    f32x16 s0 = 0.f, s1 = 0.f;
#pragma unroll
    for (int ks = 0; ks < 4; ++ks) {
      int c = (ks * 2 + hi) ^ swz;
      bf16x8 ka0 = *(const bf16x8*)(Kb + l31 * 64 + c * 8);
      bf16x8 ka1 = *(const bf16x8*)(Kb + (32 + l31) * 64 + c * 8);
      s0 = MFMA32(ka0, qf[ks], s0);
      s1 = MFMA32(ka1, qf[ks], s1);
    }

    if (t == qt) {  // causal mask (last tile only)
#pragma unroll
      for (int r = 0; r < 16; ++r) {
        int kvp = kv0 + (r & 3) + 8 * (r >> 2) + 4 * hi;
        if (kvp > qcol)      s0[r] = -__builtin_inff();
        if (kvp + 32 > qcol) s1[r] = -__builtin_inff();
      }
    }

    // defer-max (fast path: no shuffles, no rescale)
    float pm = fmaxf(s0[0], s1[0]);
#pragma unroll
    for (int r = 1; r < 16; ++r) pm = fmaxf(pm, fmaxf(s0[r], s1[r]));
    if (!__all(pm <= mreg + 8.f)) {
      float t0 = fmaxf(pm, __shfl_xor(pm, 32));
      float mn = fmaxf(mreg, t0);
      float esc = exp2f(mreg - mn);
      mreg = mn; ll *= esc;
#pragma unroll
      for (int r = 0; r < 16; ++r) { o0[r] *= esc; o1[r] *= esc; }
    }

    // P = exp2(S^T - m); row-sums; in-register pack to PV B-fragments
    float p[32];
#pragma unroll
    for (int r = 0; r < 16; ++r) {
      p[r]      = exp2f(s0[r] - mreg);
      p[16 + r] = exp2f(s1[r] - mreg);
    }
    float ps = p[0];
#pragma unroll
    for (int r = 1; r < 32; ++r) ps += p[r];
    ps += __shfl_xor(ps, 32);
    ll += ps;

    bf16x8 pf[2][2];
#pragma unroll
    for (int kvsub = 0; kvsub < 2; ++kvsub)
#pragma unroll
      for (int ks = 0; ks < 2; ++ks) {
        const int off = kvsub * 16 + ks * 8;
        unsigned a1, b1, a2, b2;
        asm("v_cvt_pk_bf16_f32 %0, %1, %2" : "=v"(a1) : "v"(p[off + 0]), "v"(p[off + 1]));
        asm("v_cvt_pk_bf16_f32 %0, %1, %2" : "=v"(b1) : "v"(p[off + 4]), "v"(p[off + 5]));
        asm("v_cvt_pk_bf16_f32 %0, %1, %2" : "=v"(a2) : "v"(p[off + 2]), "v"(p[off + 3]));
        asm("v_cvt_pk_bf16_f32 %0, %1, %2" : "=v"(b2) : "v"(p[off + 6]), "v"(p[off + 7]));
        asm("v_permlane32_swap_b32 %0, %1" : "+v"(a1), "+v"(b1));
        asm("v_permlane32_swap_b32 %0, %1" : "+v"(a2), "+v"(b2));
        union { unsigned u[4]; bf16x8 f; } fr;
        fr.u[0] = a1; fr.u[1] = a2; fr.u[2] = b1; fr.u[3] = b2;
        pf[kvsub][ks] = fr.f;
      }

    // O^T += V^T * P^T: A = V rows d, k = kv; B = P frags (in reg)
#pragma unroll
    for (int kvsub = 0; kvsub < 2; ++kvsub)
#pragma unroll
      for (int ks = 0; ks < 2; ++ks) {
        int c = (kvsub * 4 + ks * 2 + hi) ^ swz;
        bf16x8 va0 = *(const bf16x8*)(Vb + l31 * 64 + c * 8);
        bf16x8 va1 = *(const bf16x8*)(Vb + (32 + l31) * 64 + c * 8);
        o0 = MFMA32(va0, pf[kvsub][ks], o0);
        o1 = MFMA32(va1, pf[kvsub][ks], o1);
      }
    __syncthreads();
  }

  // epilogue: O^T/ll -> bf16, bounce through retired Ks (wave-private 4KB slab)
  unsigned short* slab = &Ks[0][w * 2048];
  float inv = 1.f / ll;
#pragma unroll
  for (int i = 0; i < 8; ++i) {
    const int r = 2 * i;
    const int d0 = (r & 3) + 8 * (r >> 2) + 4 * hi;   // dsub0 d-pair start
    unsigned u0, u1;
    asm("v_cvt_pk_bf16_f32 %0, %1, %2" : "=v"(u0) : "v"(o0[r] * inv), "v"(o0[r + 1] * inv));
    asm("v_cvt_pk_bf16_f32 %0, %1, %2" : "=v"(u1) : "v"(o1[r] * inv), "v"(o1[r + 1] * inv));
    *(unsigned*)(slab + l31 * 64 + (((d0 >> 3) ^ (l31 & 7)) * 8) + (d0 & 7)) = u0;
    const int d1 = 32 + d0;
    *(unsigned*)(slab + l31 * 64 + (((d1 >> 3) ^ (l31 & 7)) * 8) + (d1 & 7)) = u1;
  }
  unsigned short* op = Og + (size_t)bb * 2048 * 1024 + (size_t)hh * 64;
#pragma unroll
  for (int it = 0; it < 4; ++it) {
    int ci = it * 64 + lane;
    int qr = ci >> 3, c = ci & 7;
    short8 vv = *(const short8*)(slab + qr * 64 + ((c ^ (qr & 7)) * 8));
    *(short8*)(op + (size_t)(wq + qr) * 1024 + c * 8) = vv;
  }
}

extern "C" void kernel_launch(void* const* d_in, const int* in_sizes, int n_in,
                              void* d_out, int out_size, void* d_ws, size_t ws_size,
                              hipStream_t stream) {
  const float* x    = (const float*)d_in[0];
  const float* Wqkv = (const float*)d_in[1];
  const float* Wout = (const float*)d_in[2];
  float* out = (float*)d_out;

  char* ws = (char*)d_ws;
  unsigned short* xb  = (unsigned short*)(ws);                              // 8 MB
  unsigned short* wqb = (unsigned short*)(ws + (size_t)8 * 1024 * 1024);    // 6 MB
  unsigned short* wob = (unsigned short*)(ws + (size_t)14 * 1024 * 1024);   // 2 MB
  unsigned short* qkv = (unsigned short*)(ws + (size_t)16 * 1024 * 1024);   // 24 MB
  unsigned short* att = (unsigned short*)(ws + (size_t)40 * 1024 * 1024);   // 8 MB

  static bool attr_set = false;
  if (!attr_set) {
    hipFuncSetAttribute((const void*)gemm_qkv_8ph,
                        hipFuncAttributeMaxDynamicSharedMemorySize, 131072);
    attr_set = true;
  }

  cvt3_kernel<<<2048, 256, 0, stream>>>(x, 4194304 / 4, Wqkv, 3145728 / 4,
                                        Wout, 1048576 / 4, xb, wqb, wob);

  // QKV projection (8-phase 256^2) -> Q,K [bh][s][dk] (Q exp2-scaled); V^T [bh][dk][s]
  gemm_qkv_8ph<<<dim3(12, 16), 512, 131072, stream>>>(xb, wqb, qkv);

  const unsigned short* Qp  = qkv;
  const unsigned short* Kp  = qkv + 4194304;
  const unsigned short* Vtp = qkv + 8388608;
  attn_kernel<<<1024, 128, 0, stream>>>(Qp, Kp, Vtp, att);

  // output projection -> fp32 out
  gemm_out<<<dim3(8, 32), 256, 32768, stream>>>(att, wob, out, 4096, 1024, 1024);
}